// Round 1
// baseline (2084.582 us; speedup 1.0000x reference)
//
#include <hip/hip_runtime.h>

#define NB 4
#define NH 32
#define SNEW 2048
#define DH 128
#define MAXLEN 4096

typedef __attribute__((ext_vector_type(8))) short bf16x8;   // 8 bf16 (4 VGPR)
typedef __attribute__((ext_vector_type(4))) float f32x4;    // MFMA C/D frag

#if __has_builtin(__builtin_amdgcn_exp2f)
#define EXP2(x) __builtin_amdgcn_exp2f(x)
#else
#define EXP2(x) exp2f(x)
#endif

static __device__ __forceinline__ unsigned short bf16rne(float f) {
  unsigned int u = __builtin_bit_cast(unsigned int, f);
  u += 0x7FFFu + ((u >> 16) & 1u);
  return (unsigned short)(u >> 16);
}

// ---------------------------------------------------------------------------
// Splice: new_cache = concat(cache[:start], new, cache[end:]) for K and V.
// Pure HBM-bound float4 copy. start/end read from device scalars (general).
// ---------------------------------------------------------------------------
__global__ void splice_kernel(const float4* __restrict__ k4,
                              const float4* __restrict__ v4,
                              const float4* __restrict__ kc4,
                              const float4* __restrict__ vc4,
                              const int* __restrict__ sp,
                              const int* __restrict__ ep,
                              float4* __restrict__ nk4,
                              float4* __restrict__ nv4) {
  const int start = *sp, end = *ep;
  const int total = NB * NH * MAXLEN * (DH / 4);  // 16,777,216
  for (int i = blockIdx.x * blockDim.x + threadIdx.x; i < total;
       i += gridDim.x * blockDim.x) {
    int d4 = i & 31;
    int s  = (i >> 5) & (MAXLEN - 1);
    int bh = i >> 17;
    float4 kv, vv;
    if (s >= start && s < end) {
      size_t src = ((size_t)bh * SNEW + (s - start)) * (DH / 4) + d4;
      kv = k4[src];
      vv = v4[src];
    } else {
      kv = kc4[i];
      vv = vc4[i];
    }
    nk4[i] = kv;
    nv4[i] = vv;
  }
}

// ---------------------------------------------------------------------------
// Flash attention, causal (top-left aligned: q row i attends cache j <= i).
// Reads the spliced caches (correct for any start/end since i < Lq <= end).
// 4 warps/block; warp w owns q rows [qb+32w, qb+32w+32). KVBLK=32.
// bf16 MFMA 16x16x32, fp32 accum. exp2 with scale*log2e folded into Q.
//
// LDS layouts (all 16B-granular XOR swizzles, write side == read side):
//   smK : K [kv=32][d=128] bf16, row 256B, bytecol ^= (kv&3)<<4
//   smV : V^T [d=128][kv=32] bf16, row 64B, bytecol ^= ((d>>2)&3)<<4
//   smP : per-warp P [q=32][kv=32] bf16, row 64B, bytecol ^= ((q>>2)&3)<<4
// ---------------------------------------------------------------------------
__global__ __launch_bounds__(256, 2) void attn_kernel(
    const float* __restrict__ q,
    const float* __restrict__ kc,
    const float* __restrict__ vc,
    float* __restrict__ out) {
  const int tid = threadIdx.x;
  const int w   = tid >> 6;
  const int l   = tid & 63;
  const int l15 = l & 15;
  const int g   = l >> 4;          // 0..3
  const int bh  = blockIdx.y;
  const int qb  = blockIdx.x * 128;

  __shared__ __align__(16) unsigned char smK[8192];
  __shared__ __align__(16) unsigned char smV[8192];
  __shared__ __align__(16) unsigned char smP[8192];

  const float qscale = 0.08838834764831845f * 1.4426950408889634f; // 1/sqrt(128)*log2e

  // ---- Q fragments in registers: A[m=q][k=d], lane m=l15, k=8g+j ----
  bf16x8 qf[2][4];
  {
    const float* qbase = q + (size_t)bh * SNEW * DH;
#pragma unroll
    for (int mt = 0; mt < 2; ++mt) {
      const int row = qb + w * 32 + mt * 16 + l15;
      const float* rp = qbase + (size_t)row * DH + g * 8;
#pragma unroll
      for (int ks = 0; ks < 4; ++ks) {
        float4 a = *(const float4*)(rp + ks * 32);
        float4 b = *(const float4*)(rp + ks * 32 + 4);
        bf16x8 f;
        f[0] = (short)bf16rne(a.x * qscale);
        f[1] = (short)bf16rne(a.y * qscale);
        f[2] = (short)bf16rne(a.z * qscale);
        f[3] = (short)bf16rne(a.w * qscale);
        f[4] = (short)bf16rne(b.x * qscale);
        f[5] = (short)bf16rne(b.y * qscale);
        f[6] = (short)bf16rne(b.z * qscale);
        f[7] = (short)bf16rne(b.w * qscale);
        qf[mt][ks] = f;
      }
    }
  }

  f32x4 acc[2][8];          // [mt][ntd]: rows 4g+r+16mt, cols l15+16ntd
  float m_r[2][4], l_r[2][4];
  const f32x4 z4 = {0.f, 0.f, 0.f, 0.f};
#pragma unroll
  for (int mt = 0; mt < 2; ++mt) {
#pragma unroll
    for (int nt = 0; nt < 8; ++nt) acc[mt][nt] = z4;
#pragma unroll
    for (int r = 0; r < 4; ++r) { m_r[mt][r] = -3.0e38f; l_r[mt][r] = 0.f; }
  }

  const float* kcb = kc + (size_t)bh * MAXLEN * DH;
  const float* vcb = vc + (size_t)bh * MAXLEN * DH;
  const int kv_hi = qb + 128;      // exclusive staging bound for this block
  const int myend = qb + w * 32;   // this warp's diagonal tile base

  for (int kv0 = 0; kv0 < kv_hi; kv0 += 32) {
    // ---- cooperative stage: K -> smK (bf16), V -> smV transposed (bf16) ----
#pragma unroll
    for (int i = 0; i < 4; ++i) {
      int idx = i * 256 + tid;
      int kvr = idx >> 5;   // 0..31
      int dq  = idx & 31;   // float4 index along d
      const float4 kk = *(const float4*)(kcb + (size_t)(kv0 + kvr) * DH + dq * 4);
      const float4 vv = *(const float4*)(vcb + (size_t)(kv0 + kvr) * DH + dq * 4);
      unsigned int koff = kvr * 256 + ((dq * 8) ^ ((kvr & 3) << 4));
      ushort4 kb;
      kb.x = bf16rne(kk.x); kb.y = bf16rne(kk.y);
      kb.z = bf16rne(kk.z); kb.w = bf16rne(kk.w);
      *(ushort4*)(smK + koff) = kb;
      const float vvv[4] = {vv.x, vv.y, vv.z, vv.w};
#pragma unroll
      for (int jj = 0; jj < 4; ++jj) {
        int d = dq * 4 + jj;
        unsigned int voff = d * 64 + ((kvr * 2) ^ (((d >> 2) & 3) << 4));
        *(unsigned short*)(smV + voff) = bf16rne(vvv[jj]);
      }
    }
    __syncthreads();

    if (kv0 <= myend) {
      // ---- QK^T: S[mt][nt], C rows 4g+r (+16mt), cols l15 (+16nt) ----
      f32x4 S[2][2];
#pragma unroll
      for (int mt = 0; mt < 2; ++mt)
#pragma unroll
        for (int nt = 0; nt < 2; ++nt) S[mt][nt] = z4;
#pragma unroll
      for (int ks = 0; ks < 4; ++ks) {
        bf16x8 kf[2];
#pragma unroll
        for (int nt = 0; nt < 2; ++nt) {
          int rowk = l15 + nt * 16;
          unsigned int off =
              rowk * 256 + (((ks * 64) + g * 16) ^ ((rowk & 3) << 4));
          kf[nt] = *(const bf16x8*)(smK + off);
        }
#pragma unroll
        for (int mt = 0; mt < 2; ++mt)
#pragma unroll
          for (int nt = 0; nt < 2; ++nt)
            S[mt][nt] = __builtin_amdgcn_mfma_f32_16x16x32_bf16(
                qf[mt][ks], kf[nt], S[mt][nt], 0, 0, 0);
      }

      if (kv0 == myend) {
        // causal mask on diagonal tile: kv_local > q_local -> -inf-ish
#pragma unroll
        for (int mt = 0; mt < 2; ++mt)
#pragma unroll
          for (int nt = 0; nt < 2; ++nt)
#pragma unroll
            for (int r = 0; r < 4; ++r)
              if (l15 + nt * 16 > mt * 16 + g * 4 + r) S[mt][nt][r] = -3.0e38f;
      }

      // ---- online softmax (rows spread over 16 lanes of the col group) ----
#pragma unroll
      for (int mt = 0; mt < 2; ++mt) {
#pragma unroll
        for (int r = 0; r < 4; ++r) {
          float mx = fmaxf(S[mt][0][r], S[mt][1][r]);
          mx = fmaxf(mx, __shfl_xor(mx, 1));
          mx = fmaxf(mx, __shfl_xor(mx, 2));
          mx = fmaxf(mx, __shfl_xor(mx, 4));
          mx = fmaxf(mx, __shfl_xor(mx, 8));
          float mnew = fmaxf(m_r[mt][r], mx);
          float fsc  = EXP2(m_r[mt][r] - mnew);
          m_r[mt][r] = mnew;
          float p0 = EXP2(S[mt][0][r] - mnew);
          float p1 = EXP2(S[mt][1][r] - mnew);
          S[mt][0][r] = p0;
          S[mt][1][r] = p1;
          float sum = p0 + p1;
          sum += __shfl_xor(sum, 1);
          sum += __shfl_xor(sum, 2);
          sum += __shfl_xor(sum, 4);
          sum += __shfl_xor(sum, 8);
          l_r[mt][r] = l_r[mt][r] * fsc + sum;
#pragma unroll
          for (int ntd = 0; ntd < 8; ++ntd) acc[mt][ntd][r] *= fsc;
        }
      }

      // ---- P -> per-warp LDS (bf16) so it can be re-read as PV A-frag ----
      const unsigned int pbase = w * 2048;
#pragma unroll
      for (int mt = 0; mt < 2; ++mt)
#pragma unroll
        for (int nt = 0; nt < 2; ++nt)
#pragma unroll
          for (int r = 0; r < 4; ++r) {
            int prow = mt * 16 + g * 4 + r;
            int pcol = l15 + nt * 16;
            unsigned int poff =
                pbase + prow * 64 + ((pcol * 2) ^ (((prow >> 2) & 3) << 4));
            *(unsigned short*)(smP + poff) = bf16rne(S[mt][nt][r]);
          }

      // ---- PV: A = P[q][kv] (rows l15+16mt, k=8g+j), B = V^T reads ----
      bf16x8 pf[2];
#pragma unroll
      for (int mt = 0; mt < 2; ++mt) {
        int prow = l15 + mt * 16;
        unsigned int poff =
            pbase + prow * 64 + ((g * 16) ^ (((prow >> 2) & 3) << 4));
        pf[mt] = *(const bf16x8*)(smP + poff);
      }
#pragma unroll
      for (int ntd = 0; ntd < 8; ++ntd) {
        int dv = l15 + ntd * 16;
        unsigned int voff = dv * 64 + ((g * 16) ^ (((dv >> 2) & 3) << 4));
        bf16x8 vf = *(const bf16x8*)(smV + voff);
#pragma unroll
        for (int mt = 0; mt < 2; ++mt)
          acc[mt][ntd] = __builtin_amdgcn_mfma_f32_16x16x32_bf16(
              pf[mt], vf, acc[mt][ntd], 0, 0, 0);
      }
    }
    __syncthreads();
  }

  // ---- epilogue: O = acc / l ----
  float* ob = out + (size_t)bh * SNEW * DH;
#pragma unroll
  for (int mt = 0; mt < 2; ++mt)
#pragma unroll
    for (int r = 0; r < 4; ++r) {
      int orow = qb + w * 32 + mt * 16 + g * 4 + r;
      float inv = 1.0f / l_r[mt][r];
      float* orp = ob + (size_t)orow * DH + l15;
#pragma unroll
      for (int ntd = 0; ntd < 8; ++ntd)
        orp[ntd * 16] = acc[mt][ntd][r] * inv;
    }
}

// ---------------------------------------------------------------------------
extern "C" void kernel_launch(void* const* d_in, const int* in_sizes, int n_in,
                              void* d_out, int out_size, void* d_ws,
                              size_t ws_size, hipStream_t stream) {
  const float* q  = (const float*)d_in[0];
  const float* k  = (const float*)d_in[1];
  const float* v  = (const float*)d_in[2];
  const float* kc = (const float*)d_in[3];
  const float* vc = (const float*)d_in[4];
  const int* sp   = (const int*)d_in[5];
  const int* ep   = (const int*)d_in[6];

  float* out = (float*)d_out;                       // [B,H,SNEW,D]
  float* nk  = out + (size_t)NB * NH * SNEW * DH;   // new_key_cache
  float* nv  = nk + (size_t)NB * NH * MAXLEN * DH;  // new_value_cache

  splice_kernel<<<2048, 256, 0, stream>>>(
      (const float4*)k, (const float4*)v, (const float4*)kc, (const float4*)vc,
      sp, ep, (float4*)nk, (float4*)nv);

  dim3 grid(SNEW / 128, NB * NH);
  attn_kernel<<<grid, 256, 0, stream>>>(q, nk, nv, out);
}